// Round 1
// baseline (186.212 us; speedup 1.0000x reference)
//
#include <hip/hip_runtime.h>
#include <hip/hip_bf16.h>
#include <math.h>

// ---------------------------------------------------------------------------
// Problem: QuanvolutionAutoencoder. B=4096, fp32 in/out.
//   feats = quanv(x, theta)           [4096,784]
//   h1    = relu(feats @ W1 + b1)     [4096,512]
//   lat   = h1 @ W2 + b2              [4096,32]
//   h2    = relu(lat @ W3 + b3)       [4096,512]
//   out   = sigmoid(h2 @ W4 + b4)     [4096,784]
// ---------------------------------------------------------------------------

#define BATCH   4096
#define NPATCH  196            // 14*14
#define FEATDIM 784            // 196*4

// ---------------------------------------------------------------------------
// Kernel 1: compose the 8 CRY gates into a single real 16x16 unitary U.
// One thread per column j: column = G8*...*G1 * e_j.
// Wire w maps to bit (3-w) of the state index (axis 'a' is the slowest).
// ---------------------------------------------------------------------------
__global__ void build_U_kernel(const float* __restrict__ theta,
                               float* __restrict__ U) {
    int j = threadIdx.x;
    if (j >= 16) return;
    // PAIRS = [(0,1),(1,2),(2,3),(3,0),(0,2),(1,3),(2,0),(3,1)], bit = 3-wire
    const int cb[8] = {3, 2, 1, 0, 3, 2, 1, 0};
    const int tb[8] = {2, 1, 0, 3, 1, 0, 3, 2};
    float v[16];
#pragma unroll
    for (int s = 0; s < 16; ++s) v[s] = (s == j) ? 1.0f : 0.0f;
    for (int k = 0; k < 8; ++k) {
        float th = theta[k] * 0.5f;
        float ct, st;
        __sincosf(th, &st, &ct);
        int cm = 1 << cb[k];
        int tm = 1 << tb[k];
#pragma unroll
        for (int s = 0; s < 16; ++s) {
            if ((s & cm) && !(s & tm)) {
                float v0 = v[s];
                float v1 = v[s | tm];
                v[s]      = ct * v0 - st * v1;
                v[s | tm] = st * v0 + ct * v1;
            }
        }
    }
#pragma unroll
    for (int s = 0; s < 16; ++s) U[s * 16 + j] = v[s];
}

// ---------------------------------------------------------------------------
// Kernel 2: quanvolution. One thread per (batch, patch).
// feats[b, p*4 + w] = sum_s sign_w(s) * (U @ a)_s^2
// ---------------------------------------------------------------------------
__global__ __launch_bounds__(256)
void quanv_kernel(const float* __restrict__ x, const float* __restrict__ U,
                  float* __restrict__ feats) {
    __shared__ float Us[16][16];
    int tid = threadIdx.x;
    Us[tid >> 4][tid & 15] = U[tid];
    __syncthreads();

    int n = blockIdx.x * 256 + tid;
    int b = n / NPATCH;
    int p = n % NPATCH;
    int r = p / 14;
    int c = p % 14;

    const float* img = x + (size_t)b * FEATDIM;
    float a0 = img[(2 * r) * 28 + 2 * c];
    float a1 = img[(2 * r) * 28 + 2 * c + 1];
    float a2 = img[(2 * r + 1) * 28 + 2 * c];
    float a3 = img[(2 * r + 1) * 28 + 2 * c + 1];

    float amp[4][2];
    __sincosf(a0 * 0.5f, &amp[0][1], &amp[0][0]);
    __sincosf(a1 * 0.5f, &amp[1][1], &amp[1][0]);
    __sincosf(a2 * 0.5f, &amp[2][1], &amp[2][0]);
    __sincosf(a3 * 0.5f, &amp[3][1], &amp[3][0]);

    float av[16];
#pragma unroll
    for (int s = 0; s < 16; ++s) {
        av[s] = amp[0][(s >> 3) & 1] * amp[1][(s >> 2) & 1] *
                amp[2][(s >> 1) & 1] * amp[3][s & 1];
    }

    float m0 = 0.f, m1 = 0.f, m2 = 0.f, m3 = 0.f;
#pragma unroll
    for (int s = 0; s < 16; ++s) {
        float vv = 0.f;
#pragma unroll
        for (int t = 0; t < 16; ++t) vv += Us[s][t] * av[t];
        float pr = vv * vv;
        m0 += ((s >> 3) & 1) ? -pr : pr;
        m1 += ((s >> 2) & 1) ? -pr : pr;
        m2 += ((s >> 1) & 1) ? -pr : pr;
        m3 += (s & 1)        ? -pr : pr;
    }
    *(float4*)&feats[(size_t)b * FEATDIM + p * 4] = make_float4(m0, m1, m2, m3);
}

// ---------------------------------------------------------------------------
// Kernel 3: tiled fp32 GEMM + bias + activation.
// C[M,N] = act(A[M,K] @ B[K,N] + bias[N]); ACT: 0=none, 1=relu, 2=sigmoid.
// Requires: M % BM == 0, K % BK == 0, N % 4 == 0, TN == 4.
// ---------------------------------------------------------------------------
template <int BM, int BN, int BK, int TM, int TN, int ACT>
__global__ __launch_bounds__((BM / TM) * (BN / TN))
void gemm_bias_act(const float* __restrict__ A, const float* __restrict__ B,
                   const float* __restrict__ bias, float* __restrict__ C,
                   int M, int N, int K) {
    constexpr int TX = BN / TN;
    constexpr int TY = BM / TM;
    constexpr int NT = TX * TY;
    constexpr int AV = (BM * BK) / (NT * 4);
    constexpr int BV = (BK * BN) / (NT * 4);

    __shared__ float As[BM][BK + 4];
    __shared__ float Bs[BK][BN + 4];

    const int tid = threadIdx.x;
    const int tx = tid % TX;
    const int ty = tid / TX;
    const int row0 = blockIdx.y * BM;
    const int col0 = blockIdx.x * BN;

    float acc[TM][TN] = {};

    for (int k0 = 0; k0 < K; k0 += BK) {
#pragma unroll
        for (int i = 0; i < AV; ++i) {
            int idx = (tid + i * NT) * 4;
            int ar = idx / BK;
            int ac = idx % BK;
            float4 v = *(const float4*)(A + (size_t)(row0 + ar) * K + k0 + ac);
            *(float4*)&As[ar][ac] = v;
        }
#pragma unroll
        for (int i = 0; i < BV; ++i) {
            int idx = (tid + i * NT) * 4;
            int br = idx / BN;
            int bc = idx % BN;
            int col = col0 + bc;
            float4 v;
            if (col < N)
                v = *(const float4*)(B + (size_t)(k0 + br) * N + col);
            else
                v = make_float4(0.f, 0.f, 0.f, 0.f);
            *(float4*)&Bs[br][bc] = v;
        }
        __syncthreads();
#pragma unroll
        for (int k = 0; k < BK; ++k) {
            float a[TM];
#pragma unroll
            for (int i = 0; i < TM; ++i) a[i] = As[ty * TM + i][k];
            float4 bv = *(const float4*)&Bs[k][tx * TN];
            float bj[4] = {bv.x, bv.y, bv.z, bv.w};
#pragma unroll
            for (int i = 0; i < TM; ++i)
#pragma unroll
                for (int j = 0; j < TN; ++j) acc[i][j] += a[i] * bj[j];
        }
        __syncthreads();
    }

    int col = col0 + tx * TN;
    if (col < N) {
        float4 bb = *(const float4*)(bias + col);
        float bj[4] = {bb.x, bb.y, bb.z, bb.w};
#pragma unroll
        for (int i = 0; i < TM; ++i) {
            float o[4];
#pragma unroll
            for (int j = 0; j < 4; ++j) {
                float v = acc[i][j] + bj[j];
                if constexpr (ACT == 1) v = v > 0.f ? v : 0.f;
                if constexpr (ACT == 2) v = 1.0f / (1.0f + __expf(-v));
                o[j] = v;
            }
            *(float4*)(C + (size_t)(row0 + ty * TM + i) * N + col) =
                make_float4(o[0], o[1], o[2], o[3]);
        }
    }
}

// ---------------------------------------------------------------------------
extern "C" void kernel_launch(void* const* d_in, const int* in_sizes, int n_in,
                              void* d_out, int out_size, void* d_ws, size_t ws_size,
                              hipStream_t stream) {
    const float* x     = (const float*)d_in[0];
    const float* theta = (const float*)d_in[1];
    const float* W1    = (const float*)d_in[2];
    const float* b1    = (const float*)d_in[3];
    const float* W2    = (const float*)d_in[4];
    const float* b2    = (const float*)d_in[5];
    const float* W3    = (const float*)d_in[6];
    const float* b3    = (const float*)d_in[7];
    const float* W4    = (const float*)d_in[8];
    const float* b4    = (const float*)d_in[9];
    float* out = (float*)d_out;

    // workspace layout (floats)
    float* U     = (float*)d_ws;                    // 256
    float* feats = U + 256;                         // 4096*784
    float* h1    = feats + (size_t)BATCH * FEATDIM; // 4096*512
    float* lat   = h1 + (size_t)BATCH * 512;        // 4096*32
    float* h2    = lat + (size_t)BATCH * 32;        // 4096*512

    build_U_kernel<<<1, 16, 0, stream>>>(theta, U);

    int npix = BATCH * NPATCH;  // 802816, divisible by 256
    quanv_kernel<<<npix / 256, 256, 0, stream>>>(x, U, feats);

    // GEMM1: [4096,784] @ [784,512] + b1, relu -> h1
    {
        dim3 grid(512 / 64, BATCH / 64);
        gemm_bias_act<64, 64, 16, 4, 4, 1><<<grid, 256, 0, stream>>>(
            feats, W1, b1, h1, BATCH, 512, FEATDIM);
    }
    // GEMM2: [4096,512] @ [512,32] + b2 -> lat
    {
        dim3 grid(1, BATCH / 64);
        gemm_bias_act<64, 32, 16, 4, 4, 0><<<grid, 128, 0, stream>>>(
            h1, W2, b2, lat, BATCH, 32, 512);
    }
    // GEMM3: [4096,32] @ [32,512] + b3, relu -> h2
    {
        dim3 grid(512 / 64, BATCH / 64);
        gemm_bias_act<64, 64, 16, 4, 4, 1><<<grid, 256, 0, stream>>>(
            lat, W3, b3, h2, BATCH, 512, 32);
    }
    // GEMM4: [4096,512] @ [512,784] + b4, sigmoid -> out
    {
        dim3 grid((FEATDIM + 63) / 64, BATCH / 64);
        gemm_bias_act<64, 64, 16, 4, 4, 2><<<grid, 256, 0, stream>>>(
            h2, W4, b4, out, BATCH, FEATDIM, 512);
    }
}

// Round 2
// 81.640 us; speedup vs baseline: 2.2809x; 2.2809x over previous
//
#include <hip/hip_runtime.h>
#include <hip/hip_bf16.h>
#include <math.h>

// ---------------------------------------------------------------------------
// QuanvolutionAutoencoder, B=4096, fp32 in/out.
//   feats = quanv(x, theta)                     [4096,784]
//   h1    = relu(feats @ W1 + b1)               [4096,512]
//   h2    = relu(h1 @ (W2@W3) + (b2@W3 + b3))   [4096,512]   (GEMM2+3 fused)
//   out   = sigmoid(h2 @ W4 + b4)               [4096,784]
// GEMMs run as bf16 MFMA (16x16x32), fp32 accumulate.
// ---------------------------------------------------------------------------

#define BATCH   4096
#define NPATCH  196
#define FEATDIM 784
#define KP1     832     // K for GEMM1 padded to 13*64
#define NP4     832     // N for GEMM4 padded to 13*64

typedef __bf16 b8 __attribute__((ext_vector_type(8)));
typedef float  f4 __attribute__((ext_vector_type(4)));

__device__ __forceinline__ unsigned short f2bf(float f) {
    unsigned u = __float_as_uint(f);
    u += 0x7FFF + ((u >> 16) & 1);          // round-to-nearest-even
    return (unsigned short)(u >> 16);
}

__device__ __forceinline__ void gload16(const void* g, void* l) {
    __builtin_amdgcn_global_load_lds(
        (const __attribute__((address_space(1))) unsigned int*)g,
        (__attribute__((address_space(3))) unsigned int*)l, 16, 0, 0);
}

// ---------------------------------------------------------------------------
__global__ void zero_kernel(float4* __restrict__ p, int n4) {
    int i = blockIdx.x * 256 + threadIdx.x;
    if (i < n4) p[i] = make_float4(0.f, 0.f, 0.f, 0.f);
}

// ---------------------------------------------------------------------------
// Compose the 8 CRY gates into one real 16x16 unitary U. 16 threads.
// ---------------------------------------------------------------------------
__global__ void build_U_kernel(const float* __restrict__ theta,
                               float* __restrict__ U) {
    int j = threadIdx.x;
    if (j >= 16) return;
    const int cb[8] = {3, 2, 1, 0, 3, 2, 1, 0};
    const int tb[8] = {2, 1, 0, 3, 1, 0, 3, 2};
    float v[16];
#pragma unroll
    for (int s = 0; s < 16; ++s) v[s] = (s == j) ? 1.0f : 0.0f;
    for (int k = 0; k < 8; ++k) {
        float th = theta[k] * 0.5f;
        float ct, st;
        __sincosf(th, &st, &ct);
        int cm = 1 << cb[k];
        int tm = 1 << tb[k];
#pragma unroll
        for (int s = 0; s < 16; ++s) {
            if ((s & cm) && !(s & tm)) {
                float v0 = v[s], v1 = v[s | tm];
                v[s]      = ct * v0 - st * v1;
                v[s | tm] = st * v0 + ct * v1;
            }
        }
    }
#pragma unroll
    for (int s = 0; s < 16; ++s) U[s * 16 + j] = v[s];
}

// ---------------------------------------------------------------------------
// Quanvolution -> bf16 features, row pitch KP1 (pad cols pre-zeroed).
// ---------------------------------------------------------------------------
__global__ __launch_bounds__(256)
void quanv_kernel(const float* __restrict__ x, const float* __restrict__ U,
                  unsigned short* __restrict__ featsB) {
    __shared__ float Us[16][16];
    int tid = threadIdx.x;
    Us[tid >> 4][tid & 15] = U[tid];
    __syncthreads();

    int n = blockIdx.x * 256 + tid;
    int b = n / NPATCH;
    int p = n % NPATCH;
    int r = p / 14;
    int c = p % 14;

    const float* img = x + (size_t)b * FEATDIM;
    float a0 = img[(2 * r) * 28 + 2 * c];
    float a1 = img[(2 * r) * 28 + 2 * c + 1];
    float a2 = img[(2 * r + 1) * 28 + 2 * c];
    float a3 = img[(2 * r + 1) * 28 + 2 * c + 1];

    float amp[4][2];
    __sincosf(a0 * 0.5f, &amp[0][1], &amp[0][0]);
    __sincosf(a1 * 0.5f, &amp[1][1], &amp[1][0]);
    __sincosf(a2 * 0.5f, &amp[2][1], &amp[2][0]);
    __sincosf(a3 * 0.5f, &amp[3][1], &amp[3][0]);

    float av[16];
#pragma unroll
    for (int s = 0; s < 16; ++s)
        av[s] = amp[0][(s >> 3) & 1] * amp[1][(s >> 2) & 1] *
                amp[2][(s >> 1) & 1] * amp[3][s & 1];

    float m0 = 0.f, m1 = 0.f, m2 = 0.f, m3 = 0.f;
#pragma unroll
    for (int s = 0; s < 16; ++s) {
        float vv = 0.f;
#pragma unroll
        for (int t = 0; t < 16; ++t) vv += Us[s][t] * av[t];
        float pr = vv * vv;
        m0 += ((s >> 3) & 1) ? -pr : pr;
        m1 += ((s >> 2) & 1) ? -pr : pr;
        m2 += ((s >> 1) & 1) ? -pr : pr;
        m3 += (s & 1)        ? -pr : pr;
    }
    ushort4 o;
    o.x = f2bf(m0); o.y = f2bf(m1); o.z = f2bf(m2); o.w = f2bf(m3);
    *(ushort4*)&featsB[(size_t)b * KP1 + p * 4] = o;
}

// ---------------------------------------------------------------------------
// Transposing fp32 -> bf16 weight conversion: out[n*ldo + k] = in[k*N + n].
// ---------------------------------------------------------------------------
__global__ void convT_kernel(const float* __restrict__ in,
                             unsigned short* __restrict__ out,
                             int K, int N, int ldo) {
    int tid = blockIdx.x * 256 + threadIdx.x;
    if (tid >= K * N) return;
    int k = tid / N, n = tid % N;
    out[(size_t)n * ldo + k] = f2bf(in[tid]);
}

// Wc^T[n*512+k] = bf16( sum_i W2[k*32+i] * W3[i*512+n] )
__global__ void fuse_w23_kernel(const float* __restrict__ W2,
                                const float* __restrict__ W3,
                                unsigned short* __restrict__ WcT) {
    int tid = blockIdx.x * 256 + threadIdx.x;   // 512*512
    int n = tid >> 9, k = tid & 511;
    float s = 0.f;
#pragma unroll
    for (int i = 0; i < 32; ++i) s += W2[k * 32 + i] * W3[i * 512 + n];
    WcT[tid] = f2bf(s);
}

// bc[n] = b3[n] + sum_i b2[i] * W3[i*512+n]
__global__ void fuse_b_kernel(const float* __restrict__ W3,
                              const float* __restrict__ b2,
                              const float* __restrict__ b3,
                              float* __restrict__ bc) {
    int n = blockIdx.x * 256 + threadIdx.x;
    if (n >= 512) return;
    float s = b3[n];
#pragma unroll
    for (int i = 0; i < 32; ++i) s += b2[i] * W3[i * 512 + n];
    bc[n] = s;
}

// ---------------------------------------------------------------------------
// bf16 MFMA GEMM: C[M,N] = act(A @ B + bias), B given transposed (BT[N][K]).
// Tile 128x64x64, 256 threads = 4 waves (2M x 2N), double-buffered LDS,
// global_load_lds(16B) staging with XOR-swizzled global source so that
// ds_read_b128 fragment reads are 2-way-bank-aliased (free).
// ACT: 1=relu, 2=sigmoid. OUT_BF16: 1 -> bf16 C, 0 -> fp32 C.
// ---------------------------------------------------------------------------
template <int ACT, int OUT_BF16>
__global__ __launch_bounds__(256)
void gemm_mfma(const unsigned short* __restrict__ A,   // [M][lda] bf16
               const unsigned short* __restrict__ BT,  // [Npad][ldb] bf16
               const float* __restrict__ bias,         // [Nlog] fp32
               void* __restrict__ C,                   // [M][ldc]
               int lda, int ldb, int ldc, int Nlog, int nkt) {
    __shared__ __align__(16) unsigned short As[2][128 * 64];
    __shared__ __align__(16) unsigned short Bs[2][64 * 64];

    const int t  = threadIdx.x;
    const int w  = t >> 6;       // wave 0..3
    const int l  = t & 63;
    const int wm = w >> 1;       // 0..1  (M half)
    const int wn = w & 1;        // 0..1  (N half)
    const int row0 = blockIdx.y * 128;
    const int col0 = blockIdx.x * 64;

    // ---- staging constants: lane covers 16B chunk (row sr of 8-row group) ----
    const int sr = l >> 3;                  // 0..7
    const int sc = ((l & 7) ^ sr) * 8;      // swizzled source k-offset (elems)
    const unsigned short* Ab = A  + (size_t)(row0 + w * 8 + sr) * lda + sc;
    const unsigned short* Bb = BT + (size_t)(col0 + w * 8 + sr) * ldb + sc;

    // ---- ds_read constants ----
    const int q  = l >> 4;                  // k-quarter 0..3
    const int lx = l & 15;                  // row-within-fragment / out col
    const int sx = l & 7;                   // swizzle key
    const int coff[2] = { ((0 + q) ^ sx) * 16, ((4 + q) ^ sx) * 16 };

    f4 acc[4][2];
#pragma unroll
    for (int m = 0; m < 4; ++m)
#pragma unroll
        for (int n = 0; n < 2; ++n) acc[m][n] = (f4)0.f;

    auto stage = [&](int bi, int kt) {
        const int k0 = kt * 64;
        char* la = (char*)&As[bi][0] + w * 1024;
        char* lb = (char*)&Bs[bi][0] + w * 1024;
#pragma unroll
        for (int it = 0; it < 4; ++it)
            gload16(Ab + (size_t)(it * 32) * lda + k0, la + it * 4096);
#pragma unroll
        for (int it = 0; it < 2; ++it)
            gload16(Bb + (size_t)(it * 32) * ldb + k0, lb + it * 4096);
    };

    auto compute = [&](int bi) {
        const char* la = (const char*)&As[bi][0];
        const char* lb = (const char*)&Bs[bi][0];
#pragma unroll
        for (int kk = 0; kk < 2; ++kk) {
            const int co = coff[kk];
            b8 a[4], bf[2];
#pragma unroll
            for (int m = 0; m < 4; ++m)
                a[m] = *(const b8*)(la + (wm * 64 + m * 16 + lx) * 128 + co);
#pragma unroll
            for (int n = 0; n < 2; ++n)
                bf[n] = *(const b8*)(lb + (wn * 32 + n * 16 + lx) * 128 + co);
#pragma unroll
            for (int m = 0; m < 4; ++m)
#pragma unroll
                for (int n = 0; n < 2; ++n)
                    acc[m][n] = __builtin_amdgcn_mfma_f32_16x16x32_bf16(
                        a[m], bf[n], acc[m][n], 0, 0, 0);
        }
    };

    stage(0, 0);
    __syncthreads();
    for (int kt = 0; kt < nkt; ++kt) {
        if (kt + 1 < nkt) stage((kt + 1) & 1, kt + 1);
        compute(kt & 1);
        __syncthreads();
    }

    // ---- epilogue: C row = (lane>>4)*4 + reg, col = lane&15 ----
#pragma unroll
    for (int n = 0; n < 2; ++n) {
        int col = col0 + wn * 32 + n * 16 + lx;
        if (col >= Nlog) continue;
        float bv = bias[col];
#pragma unroll
        for (int m = 0; m < 4; ++m) {
            int row = row0 + wm * 64 + m * 16 + q * 4;
#pragma unroll
            for (int r = 0; r < 4; ++r) {
                float v = acc[m][n][r] + bv;
                if (ACT == 1) v = fmaxf(v, 0.f);
                if (ACT == 2) v = 1.0f / (1.0f + __expf(-v));
                if (OUT_BF16)
                    ((unsigned short*)C)[(size_t)(row + r) * ldc + col] = f2bf(v);
                else
                    ((float*)C)[(size_t)(row + r) * ldc + col] = v;
            }
        }
    }
}

// ---------------------------------------------------------------------------
extern "C" void kernel_launch(void* const* d_in, const int* in_sizes, int n_in,
                              void* d_out, int out_size, void* d_ws, size_t ws_size,
                              hipStream_t stream) {
    const float* x     = (const float*)d_in[0];
    const float* theta = (const float*)d_in[1];
    const float* W1    = (const float*)d_in[2];
    const float* b1    = (const float*)d_in[3];
    const float* W2    = (const float*)d_in[4];
    const float* b2    = (const float*)d_in[5];
    const float* W3    = (const float*)d_in[6];
    const float* b3    = (const float*)d_in[7];
    const float* W4    = (const float*)d_in[8];
    const float* b4    = (const float*)d_in[9];
    float* out = (float*)d_out;

    // workspace layout (all 1KB-aligned)
    char* ws = (char*)d_ws;
    float*          U      = (float*)ws;            ws += 1024;
    unsigned short* featsB = (unsigned short*)ws;   ws += (size_t)BATCH * KP1 * 2;  // 6.8 MB
    unsigned short* W1B    = (unsigned short*)ws;   ws += (size_t)512 * KP1 * 2;    // 852 KB
    unsigned short* W4B    = (unsigned short*)ws;   ws += (size_t)NP4 * 512 * 2;    // 852 KB
    unsigned short* WcT    = (unsigned short*)ws;   ws += (size_t)512 * 512 * 2;    // 524 KB
    float*          bc     = (float*)ws;            ws += 512 * 4;
    unsigned short* h1B    = (unsigned short*)ws;   ws += (size_t)BATCH * 512 * 2;  // 4.2 MB
    unsigned short* h2B    = (unsigned short*)ws;   /* 4.2 MB */

    // zero featsB + W1B + W4B (covers all pad regions; they are contiguous)
    {
        size_t zbytes = (size_t)BATCH * KP1 * 2 + (size_t)512 * KP1 * 2 +
                        (size_t)NP4 * 512 * 2;          // 8,519,680
        int n4 = (int)(zbytes / 16);
        zero_kernel<<<(n4 + 255) / 256, 256, 0, stream>>>((float4*)featsB, n4);
    }

    build_U_kernel<<<1, 16, 0, stream>>>(theta, U);

    // weight prep
    convT_kernel<<<(784 * 512) / 256, 256, 0, stream>>>(W1, W1B, 784, 512, KP1);
    convT_kernel<<<(512 * 784 + 255) / 256, 256, 0, stream>>>(W4, W4B, 512, 784, 512);
    fuse_w23_kernel<<<(512 * 512) / 256, 256, 0, stream>>>(W2, W3, WcT);
    fuse_b_kernel<<<2, 256, 0, stream>>>(W3, b2, b3, bc);

    // quanvolution
    quanv_kernel<<<(BATCH * NPATCH) / 256, 256, 0, stream>>>(x, U, featsB);

    // GEMM1: feats[4096,832] @ W1 -> h1 (relu, bf16)
    gemm_mfma<1, 1><<<dim3(512 / 64, BATCH / 128), 256, 0, stream>>>(
        featsB, W1B, b1, h1B, KP1, KP1, 512, 512, KP1 / 64);
    // GEMM3': h1[4096,512] @ Wc -> h2 (relu, bf16)
    gemm_mfma<1, 1><<<dim3(512 / 64, BATCH / 128), 256, 0, stream>>>(
        h1B, WcT, bc, h2B, 512, 512, 512, 512, 512 / 64);
    // GEMM4: h2[4096,512] @ W4 -> out (sigmoid, fp32), N=784 guarded
    gemm_mfma<2, 0><<<dim3(NP4 / 64, BATCH / 128), 256, 0, stream>>>(
        h2B, W4B, b4, out, 512, 512, FEATDIM, FEATDIM, 512 / 64);
}

// Round 3
// 59.895 us; speedup vs baseline: 3.1090x; 1.3631x over previous
//
#include <hip/hip_runtime.h>
#include <hip/hip_bf16.h>
#include <math.h>

// ---------------------------------------------------------------------------
// QuanvolutionAutoencoder, B=4096, fp32 in/out.
//   feats = quanv(x, theta)                     [4096,784]
//   h1    = relu(feats @ W1 + b1)               [4096,512]
//   h2    = relu(h1 @ (W2@W3) + (b2@W3 + b3))   [4096,512]   (GEMM2+3 fused)
//   out   = sigmoid(h2 @ W4 + b4)               [4096,784]
// 4 dispatches: mega-prep (quanv + weight prep + pad zero), then 3 MFMA GEMMs.
// ---------------------------------------------------------------------------

#define BATCH   4096
#define NPATCH  196
#define FEATDIM 784
#define KP1     832     // K for GEMM1 padded to 13*64
#define NP4     832     // N for GEMM4 padded to 13*64

typedef __bf16 b8 __attribute__((ext_vector_type(8)));
typedef float  f4 __attribute__((ext_vector_type(4)));

__device__ __forceinline__ unsigned short f2bf(float f) {
    unsigned u = __float_as_uint(f);
    u += 0x7FFF + ((u >> 16) & 1);          // round-to-nearest-even
    return (unsigned short)(u >> 16);
}

__device__ __forceinline__ void gload16(const void* g, void* l) {
    __builtin_amdgcn_global_load_lds(
        (const __attribute__((address_space(1))) unsigned int*)g,
        (__attribute__((address_space(3))) unsigned int*)l, 16, 0, 0);
}

// ---------------------------------------------------------------------------
// Mega prep kernel: block roles
//   [0, 3136)        quanv -> featsB (bf16, pitch KP1)
//   [3136, 4704)     convT W1 -> W1B[n*KP1+k]
//   [4704, 6272)     convT W4 -> W4B[n*512+k]
//   [6272, 7296)     WcT[n*512+k] = bf16(sum_i W2[k,i]*W3[i,n])
//   [7296, 7298)     bc[n] = b3[n] + sum_i b2[i]*W3[i,n]
//   [7298, 7394)     zero featsB pad cols (4096 rows x 48)
//   [7394, 7406)     zero W1B pad cols (512 rows x 48)
//   [7406, 7418)     zero W4B pad rows (48 x 512)
// ---------------------------------------------------------------------------
#define Q_BASE   0
#define C1_BASE  3136
#define C4_BASE  4704
#define FW_BASE  6272
#define FB_BASE  7296
#define ZF_BASE  7298
#define Z1_BASE  7394
#define Z4_BASE  7406
#define PREP_BLOCKS 7418

__global__ __launch_bounds__(256)
void prep_kernel(const float* __restrict__ x, const float* __restrict__ theta,
                 const float* __restrict__ W1, const float* __restrict__ W2,
                 const float* __restrict__ W3, const float* __restrict__ W4,
                 const float* __restrict__ b2, const float* __restrict__ b3,
                 unsigned short* __restrict__ featsB,
                 unsigned short* __restrict__ W1B,
                 unsigned short* __restrict__ W4B,
                 unsigned short* __restrict__ WcT,
                 float* __restrict__ bc) {
    const int bid = blockIdx.x;
    const int tid = threadIdx.x;

    if (bid < C1_BASE) {
        // ---------------- quanvolution ----------------
        __shared__ float Us[16][16];
        if (tid < 16) {
            // build column tid of U = G8*...*G1 (wire w -> bit 3-w)
            const int cb[8] = {3, 2, 1, 0, 3, 2, 1, 0};
            const int tb[8] = {2, 1, 0, 3, 1, 0, 3, 2};
            float v[16];
#pragma unroll
            for (int s = 0; s < 16; ++s) v[s] = (s == tid) ? 1.0f : 0.0f;
            for (int k = 0; k < 8; ++k) {
                float th = theta[k] * 0.5f;
                float ct, st;
                __sincosf(th, &st, &ct);
                int cm = 1 << cb[k], tm = 1 << tb[k];
#pragma unroll
                for (int s = 0; s < 16; ++s) {
                    if ((s & cm) && !(s & tm)) {
                        float v0 = v[s], v1 = v[s | tm];
                        v[s]      = ct * v0 - st * v1;
                        v[s | tm] = st * v0 + ct * v1;
                    }
                }
            }
#pragma unroll
            for (int s = 0; s < 16; ++s) Us[s][tid] = v[s];
        }
        __syncthreads();

        int n = bid * 256 + tid;
        int b = n / NPATCH;
        int p = n % NPATCH;
        int r = p / 14;
        int c = p % 14;

        const float* img = x + (size_t)b * FEATDIM;
        float a0 = img[(2 * r) * 28 + 2 * c];
        float a1 = img[(2 * r) * 28 + 2 * c + 1];
        float a2 = img[(2 * r + 1) * 28 + 2 * c];
        float a3 = img[(2 * r + 1) * 28 + 2 * c + 1];

        float amp[4][2];
        __sincosf(a0 * 0.5f, &amp[0][1], &amp[0][0]);
        __sincosf(a1 * 0.5f, &amp[1][1], &amp[1][0]);
        __sincosf(a2 * 0.5f, &amp[2][1], &amp[2][0]);
        __sincosf(a3 * 0.5f, &amp[3][1], &amp[3][0]);

        float av[16];
#pragma unroll
        for (int s = 0; s < 16; ++s)
            av[s] = amp[0][(s >> 3) & 1] * amp[1][(s >> 2) & 1] *
                    amp[2][(s >> 1) & 1] * amp[3][s & 1];

        float m0 = 0.f, m1 = 0.f, m2 = 0.f, m3 = 0.f;
#pragma unroll
        for (int s = 0; s < 16; ++s) {
            float vv = 0.f;
#pragma unroll
            for (int t = 0; t < 16; ++t) vv += Us[s][t] * av[t];
            float pr = vv * vv;
            m0 += ((s >> 3) & 1) ? -pr : pr;
            m1 += ((s >> 2) & 1) ? -pr : pr;
            m2 += ((s >> 1) & 1) ? -pr : pr;
            m3 += (s & 1)        ? -pr : pr;
        }
        ushort4 o;
        o.x = f2bf(m0); o.y = f2bf(m1); o.z = f2bf(m2); o.w = f2bf(m3);
        *(ushort4*)&featsB[(size_t)b * KP1 + p * 4] = o;
    } else if (bid < C4_BASE) {
        // ---------------- convT W1: W1B[n*KP1+k] = bf16(W1[k*512+n]) ----------------
        int idx = (bid - C1_BASE) * 256 + tid;         // 784*512
        int k = idx / 512, n = idx % 512;
        W1B[(size_t)n * KP1 + k] = f2bf(W1[idx]);
    } else if (bid < FW_BASE) {
        // ---------------- convT W4: W4B[n*512+k] = bf16(W4[k*784+n]) ----------------
        int idx = (bid - C4_BASE) * 256 + tid;         // 512*784
        int k = idx / FEATDIM, n = idx % FEATDIM;
        W4B[(size_t)n * 512 + k] = f2bf(W4[idx]);
    } else if (bid < FB_BASE) {
        // ---------------- WcT[n*512+k] ----------------
        int idx = (bid - FW_BASE) * 256 + tid;         // 512*512, idx = n*512+k
        int n = idx >> 9, k = idx & 511;
        float s = 0.f;
#pragma unroll
        for (int i = 0; i < 32; ++i) s += W2[k * 32 + i] * W3[i * 512 + n];
        WcT[idx] = f2bf(s);
    } else if (bid < ZF_BASE) {
        // ---------------- bc ----------------
        int n = (bid - FB_BASE) * 256 + tid;
        if (n < 512) {
            float s = b3[n];
#pragma unroll
            for (int i = 0; i < 32; ++i) s += b2[i] * W3[i * 512 + n];
            bc[n] = s;
        }
    } else if (bid < Z1_BASE) {
        // ---------------- zero featsB pad cols ----------------
        int idx = (bid - ZF_BASE) * 256 + tid;         // 4096*6
        int row = idx / 6, j = idx % 6;
        *(float4*)&featsB[(size_t)row * KP1 + FEATDIM + j * 8] =
            make_float4(0.f, 0.f, 0.f, 0.f);
    } else if (bid < Z4_BASE) {
        // ---------------- zero W1B pad cols ----------------
        int idx = (bid - Z1_BASE) * 256 + tid;         // 512*6
        int row = idx / 6, j = idx % 6;
        *(float4*)&W1B[(size_t)row * KP1 + FEATDIM + j * 8] =
            make_float4(0.f, 0.f, 0.f, 0.f);
    } else {
        // ---------------- zero W4B pad rows ----------------
        int idx = (bid - Z4_BASE) * 256 + tid;         // 48*512/8 = 3072
        *(float4*)&W4B[(size_t)FEATDIM * 512 + idx * 8] =
            make_float4(0.f, 0.f, 0.f, 0.f);
    }
}

// ---------------------------------------------------------------------------
// bf16 MFMA GEMM, tile 64x64x64, 256 threads = 4 waves (2M x 2N), each wave
// a 32x32 sub-tile (2x2 16x16x32 frags). Double-buffered LDS staged via
// global_load_lds(16B) with XOR-swizzled global source (verified scheme).
// ACT: 1=relu, 2=sigmoid. OUT_BF16: 1 -> bf16 C, 0 -> fp32 C.
// ---------------------------------------------------------------------------
template <int ACT, int OUT_BF16>
__global__ __launch_bounds__(256)
void gemm_mfma(const unsigned short* __restrict__ A,   // [M][lda] bf16
               const unsigned short* __restrict__ BT,  // [Npad][ldb] bf16
               const float* __restrict__ bias,         // [Nlog] fp32
               void* __restrict__ C,                   // [M][ldc]
               int lda, int ldb, int ldc, int Nlog, int nkt) {
    __shared__ __align__(16) unsigned short As[2][64 * 64];
    __shared__ __align__(16) unsigned short Bs[2][64 * 64];

    const int t  = threadIdx.x;
    const int w  = t >> 6;       // wave 0..3
    const int l  = t & 63;
    const int wm = w >> 1;       // M half
    const int wn = w & 1;        // N half
    const int row0 = blockIdx.y * 64;
    const int col0 = blockIdx.x * 64;

    // staging: lane covers 16B chunk; row sr of 8-row group; swizzled k-chunk
    const int sr = l >> 3;                  // 0..7
    const int sc = ((l & 7) ^ sr) * 8;      // source k-offset (elements)
    const unsigned short* Ab = A  + (size_t)(row0 + w * 8 + sr) * lda + sc;
    const unsigned short* Bb = BT + (size_t)(col0 + w * 8 + sr) * ldb + sc;

    // ds_read constants
    const int q  = l >> 4;                  // k-quarter 0..3
    const int lx = l & 15;
    const int sx = l & 7;                   // swizzle key (= row&7 of frag row)
    const int coff[2] = { ((0 + q) ^ sx) * 16, ((4 + q) ^ sx) * 16 };

    f4 acc[2][2];
#pragma unroll
    for (int m = 0; m < 2; ++m)
#pragma unroll
        for (int n = 0; n < 2; ++n) acc[m][n] = (f4)0.f;

    auto stage = [&](int bi, int kt) {
        const int k0 = kt * 64;
        char* la = (char*)&As[bi][0] + w * 1024;
        char* lb = (char*)&Bs[bi][0] + w * 1024;
#pragma unroll
        for (int it = 0; it < 2; ++it)
            gload16(Ab + (size_t)(it * 32) * lda + k0, la + it * 4096);
#pragma unroll
        for (int it = 0; it < 2; ++it)
            gload16(Bb + (size_t)(it * 32) * ldb + k0, lb + it * 4096);
    };

    auto compute = [&](int bi) {
        const char* la = (const char*)&As[bi][0];
        const char* lb = (const char*)&Bs[bi][0];
#pragma unroll
        for (int kk = 0; kk < 2; ++kk) {
            const int co = coff[kk];
            b8 a[2], bf[2];
#pragma unroll
            for (int m = 0; m < 2; ++m)
                a[m] = *(const b8*)(la + (wm * 32 + m * 16 + lx) * 128 + co);
#pragma unroll
            for (int n = 0; n < 2; ++n)
                bf[n] = *(const b8*)(lb + (wn * 32 + n * 16 + lx) * 128 + co);
#pragma unroll
            for (int m = 0; m < 2; ++m)
#pragma unroll
                for (int n = 0; n < 2; ++n)
                    acc[m][n] = __builtin_amdgcn_mfma_f32_16x16x32_bf16(
                        a[m], bf[n], acc[m][n], 0, 0, 0);
        }
    };

    stage(0, 0);
    __syncthreads();
    for (int kt = 0; kt < nkt; ++kt) {
        if (kt + 1 < nkt) stage((kt + 1) & 1, kt + 1);
        compute(kt & 1);
        __syncthreads();
    }

    // epilogue: C row = base + q*4 + reg, col = base + lx
#pragma unroll
    for (int n = 0; n < 2; ++n) {
        int col = col0 + wn * 32 + n * 16 + lx;
        if (col >= Nlog) continue;
        float bv = bias[col];
#pragma unroll
        for (int m = 0; m < 2; ++m) {
            int row = row0 + wm * 32 + m * 16 + q * 4;
#pragma unroll
            for (int r = 0; r < 4; ++r) {
                float v = acc[m][n][r] + bv;
                if (ACT == 1) v = fmaxf(v, 0.f);
                if (ACT == 2) v = 1.0f / (1.0f + __expf(-v));
                if (OUT_BF16)
                    ((unsigned short*)C)[(size_t)(row + r) * ldc + col] = f2bf(v);
                else
                    ((float*)C)[(size_t)(row + r) * ldc + col] = v;
            }
        }
    }
}

// ---------------------------------------------------------------------------
extern "C" void kernel_launch(void* const* d_in, const int* in_sizes, int n_in,
                              void* d_out, int out_size, void* d_ws, size_t ws_size,
                              hipStream_t stream) {
    const float* x     = (const float*)d_in[0];
    const float* theta = (const float*)d_in[1];
    const float* W1    = (const float*)d_in[2];
    const float* b1    = (const float*)d_in[3];
    const float* W2    = (const float*)d_in[4];
    const float* b2    = (const float*)d_in[5];
    const float* W3    = (const float*)d_in[6];
    const float* b3    = (const float*)d_in[7];
    const float* W4    = (const float*)d_in[8];
    const float* b4    = (const float*)d_in[9];
    float* out = (float*)d_out;

    // workspace layout
    char* ws = (char*)d_ws;
    unsigned short* featsB = (unsigned short*)ws;   ws += (size_t)BATCH * KP1 * 2;  // 6.8 MB
    unsigned short* W1B    = (unsigned short*)ws;   ws += (size_t)512 * KP1 * 2;
    unsigned short* W4B    = (unsigned short*)ws;   ws += (size_t)NP4 * 512 * 2;
    unsigned short* WcT    = (unsigned short*)ws;   ws += (size_t)512 * 512 * 2;
    float*          bc     = (float*)ws;            ws += 512 * 4;
    unsigned short* h1B    = (unsigned short*)ws;   ws += (size_t)BATCH * 512 * 2;
    unsigned short* h2B    = (unsigned short*)ws;

    prep_kernel<<<PREP_BLOCKS, 256, 0, stream>>>(
        x, theta, W1, W2, W3, W4, b2, b3, featsB, W1B, W4B, WcT, bc);

    // GEMM1: feats[4096,832] @ W1 -> h1 (relu, bf16)
    gemm_mfma<1, 1><<<dim3(512 / 64, BATCH / 64), 256, 0, stream>>>(
        featsB, W1B, b1, h1B, KP1, KP1, 512, 512, KP1 / 64);
    // GEMM3': h1[4096,512] @ Wc -> h2 (relu, bf16)
    gemm_mfma<1, 1><<<dim3(512 / 64, BATCH / 64), 256, 0, stream>>>(
        h1B, WcT, bc, h2B, 512, 512, 512, 512, 512 / 64);
    // GEMM4: h2[4096,512] @ W4 -> out (sigmoid, fp32), N=784 guarded
    gemm_mfma<2, 0><<<dim3(NP4 / 64, BATCH / 64), 256, 0, stream>>>(
        h2B, W4B, b4, out, 512, 512, FEATDIM, FEATDIM, 512 / 64);
}